// Round 2
// baseline (4995.138 us; speedup 1.0000x reference)
//
#include <hip/hip_runtime.h>
#include <hip/hip_bf16.h>

// x:[1024,3,32,32] -> conv1(3->64,3x3,SAME)+relu -> conv2(64->128,3x3,SAME)+relu
// -> meanpool HW -> fc(128->256)+b -> *mask -> sage1(256->256)+relu -> sage2(256->128)
// Output [32,32,128] fp32.
//
// Workspace (<4MB):
//  [0,512K)       pooled [1024][128]
//  [1M,2M)        z1 [1024][256]
//  [2M,3M)        z2 [1024][256]
//  [3M,+256K)     w1p [256][256]   = s1rw - s1lw/31
//  [3M+256K,+128K) w2p [128][256]  = s2rw - s2lw/31
//  [3M+512K,+288K) w2r [64][128][9] transposed conv2 weight

static __device__ __forceinline__ unsigned short f2bf(float f) {
    union { float f; unsigned u; } v; v.f = f;
    unsigned r = v.u + 0x7fff + ((v.u >> 16) & 1);   // RNE (finite inputs)
    return (unsigned short)(r >> 16);
}
static __device__ __forceinline__ float bf2f(unsigned short h) {
    union { unsigned u; float f; } v; v.u = ((unsigned)h) << 16; return v.f;
}

__global__ __launch_bounds__(256) void prep_kernel(
    const float* __restrict__ s1lw, const float* __restrict__ s1rw,
    const float* __restrict__ s2lw, const float* __restrict__ s2rw,
    const float* __restrict__ c2w,
    float* __restrict__ w1p, float* __restrict__ w2p, float* __restrict__ w2r) {
    int i = blockIdx.x * 256 + threadIdx.x;     // grid 288 -> i in [0, 73728)
    const float inv31 = 1.f / 31.f;
    if (i < 65536) w1p[i] = s1rw[i] - s1lw[i] * inv31;
    if (i < 32768) w2p[i] = s2rw[i] - s2lw[i] * inv31;
    if (i < 73728) {                            // w2r[ic][oc][k] = c2w[oc][ic][k]
        int ic = i / 1152, rem = i % 1152, oc = rem / 9, k = rem % 9;
        w2r[i] = c2w[(oc * 64 + ic) * 9 + k];
    }
}

// One block per image: conv1 -> bf16 LDS tile -> conv2 -> relu -> meanpool.
__global__ __launch_bounds__(256) void fused_conv_kernel(
    const float* __restrict__ x,  const float* __restrict__ w1,
    const float* __restrict__ b1, const float* __restrict__ w2r,
    const float* __restrict__ b2, float* __restrict__ pooled) {
    const int img = blockIdx.x;
    __shared__ float xt[3 * 34 * 34];            // 13872 B: padded input
    __shared__ unsigned short c1t[64 * 340];     // 43520 B: [ic][r 0..9][col 0..33] bf16
    __shared__ float psum[128];
    const int t = threadIdx.x;

    const float* xi = x + img * 3072;
    for (int idx = t; idx < 3 * 1156; idx += 256) {
        int c = idx / 1156, rem = idx % 1156, r = rem / 34, col = rem % 34;
        int y = r - 1, xx = col - 1;
        float v = 0.f;
        if ((unsigned)y < 32u && (unsigned)xx < 32u) v = xi[c * 1024 + y * 32 + xx];
        xt[idx] = v;
    }
    if (t < 128) psum[t] = 0.f;

    const int ry = t >> 5, cx = t & 31;
    for (int yb = 0; yb < 4; ++yb) {
        const int y0 = yb * 8;
        __syncthreads();                         // previous band's readers done
        // ---- conv1: rows y0-1 .. y0+8, all 64 channels, bf16 into c1t ----
        for (int p = t; p < 340; p += 256) {
            int r = p / 34, tc = p % 34;
            int y = y0 + r - 1, xc = tc - 1;
            if ((unsigned)y < 32u && (unsigned)xc < 32u) {
                float patch[27];
#pragma unroll
                for (int c = 0; c < 3; ++c)
#pragma unroll
                    for (int dy = 0; dy < 3; ++dy)
#pragma unroll
                        for (int dx = 0; dx < 3; ++dx)
                            patch[c * 9 + dy * 3 + dx] = xt[c * 1156 + (y + dy) * 34 + (xc + dx)];
                for (int oc = 0; oc < 64; ++oc) {
                    float a = b1[oc];            // uniform -> s_load
#pragma unroll
                    for (int k = 0; k < 27; ++k) a = fmaf(patch[k], w1[oc * 27 + k], a);
                    c1t[oc * 340 + p] = f2bf(fmaxf(a, 0.f));
                }
            } else {
                for (int oc = 0; oc < 64; ++oc) c1t[oc * 340 + p] = 0;
            }
        }
        __syncthreads();
        // ---- conv2: thread -> position (y0+ry, cx); 4 oc-blocks of 32 ----
        for (int ocb = 0; ocb < 4; ++ocb) {
            float acc[32];
#pragma unroll
            for (int o = 0; o < 32; ++o) acc[o] = b2[ocb * 32 + o];
            for (int ic = 0; ic < 64; ++ic) {
                float patch[9];
#pragma unroll
                for (int dy = 0; dy < 3; ++dy)
#pragma unroll
                    for (int dx = 0; dx < 3; ++dx)
                        patch[dy * 3 + dx] = bf2f(c1t[ic * 340 + (ry + dy) * 34 + (cx + dx)]);
                const float* wp = w2r + (ic * 128 + ocb * 32) * 9;  // 288 consecutive floats
#pragma unroll
                for (int o = 0; o < 32; ++o)
#pragma unroll
                    for (int k = 0; k < 9; ++k)
                        acc[o] = fmaf(patch[k], wp[o * 9 + k], acc[o]);  // wp -> s_load
            }
#pragma unroll
            for (int o = 0; o < 32; ++o) {
                float v = fmaxf(acc[o], 0.f);
#pragma unroll
                for (int off = 32; off > 0; off >>= 1) v += __shfl_down(v, off);
                if ((t & 63) == 0) atomicAdd(&psum[ocb * 32 + o], v);
            }
        }
    }
    __syncthreads();
    if (t < 128) pooled[img * 128 + t] = psum[t] * (1.f / 1024.f);
}

__global__ __launch_bounds__(256) void fc_kernel(
    const float* __restrict__ pooled, const float* __restrict__ fw,
    const float* __restrict__ fb, const float* __restrict__ mask,
    float* __restrict__ z1) {
    const int img = blockIdx.x;
    __shared__ float m[128];
    const int t = threadIdx.x;
    if (t < 128) m[t] = pooled[img * 128 + t];
    __syncthreads();
    float acc = fb[t];
#pragma unroll 4
    for (int c = 0; c < 128; ++c) acc = fmaf(m[c], fw[t * 128 + c], acc);
    z1[img * 256 + t] = acc * mask[img];
}

// sage: out[i][o] = (relu of) lb[o] + (sum_j h_j/31).lw[o] + h_i.(rw-lw/31)[o]
__global__ __launch_bounds__(256) void sage1_kernel(
    const float* __restrict__ z1, const float* __restrict__ lw,
    const float* __restrict__ lb, const float* __restrict__ w1p,
    float* __restrict__ z2) {
    const int bb = blockIdx.x;
    __shared__ float h[32 * 256];
    __shared__ float sl[256];
    const int t = threadIdx.x;
    const float* zb = z1 + bb * 8192;
    for (int idx = t; idx < 8192; idx += 256) h[idx] = zb[idx];
    __syncthreads();
    float s = 0.f;
#pragma unroll
    for (int n = 0; n < 32; ++n) s += h[n * 256 + t];
    sl[t] = s * (1.f / 31.f);
    __syncthreads();
    float c = lb[t];
#pragma unroll 4
    for (int d = 0; d < 256; ++d) c = fmaf(sl[d], lw[t * 256 + d], c);
    for (int i = 0; i < 32; ++i) {
        float a = c;
#pragma unroll 4
        for (int d = 0; d < 256; ++d) a = fmaf(h[i * 256 + d], w1p[t * 256 + d], a);
        z2[(bb * 32 + i) * 256 + t] = fmaxf(a, 0.f);
    }
}

__global__ __launch_bounds__(256) void sage2_kernel(
    const float* __restrict__ z2, const float* __restrict__ lw,
    const float* __restrict__ lb, const float* __restrict__ w2p,
    float* __restrict__ out) {
    const int bb = blockIdx.x;
    __shared__ float h[32 * 256];
    __shared__ float sl[256];
    const int t = threadIdx.x;
    const float* zb = z2 + bb * 8192;
    for (int idx = t; idx < 8192; idx += 256) h[idx] = zb[idx];
    __syncthreads();
    float s = 0.f;
#pragma unroll
    for (int n = 0; n < 32; ++n) s += h[n * 256 + t];
    sl[t] = s * (1.f / 31.f);
    __syncthreads();
    const int o = t & 127, ihalf = t >> 7;
    float c = lb[o];
#pragma unroll 4
    for (int d = 0; d < 256; ++d) c = fmaf(sl[d], lw[o * 256 + d], c);
    for (int i = ihalf * 16; i < ihalf * 16 + 16; ++i) {
        float a = c;
#pragma unroll 4
        for (int d = 0; d < 256; ++d) a = fmaf(h[i * 256 + d], w2p[o * 256 + d], a);
        out[(bb * 32 + i) * 128 + o] = a;
    }
}

extern "C" void kernel_launch(void* const* d_in, const int* in_sizes, int n_in,
                              void* d_out, int out_size, void* d_ws, size_t ws_size,
                              hipStream_t stream) {
    const float* x    = (const float*)d_in[0];
    const float* mask = (const float*)d_in[1];
    const float* c1w  = (const float*)d_in[2];
    const float* c1b  = (const float*)d_in[3];
    const float* c2w  = (const float*)d_in[4];
    const float* c2b  = (const float*)d_in[5];
    const float* fcw  = (const float*)d_in[6];
    const float* fcb  = (const float*)d_in[7];
    const float* s1lw = (const float*)d_in[8];
    const float* s1lb = (const float*)d_in[9];
    const float* s1rw = (const float*)d_in[10];
    const float* s2lw = (const float*)d_in[11];
    const float* s2lb = (const float*)d_in[12];
    const float* s2rw = (const float*)d_in[13];
    float* out = (float*)d_out;

    char* ws = (char*)d_ws;
    float* pooled = (float*)(ws);
    float* z1     = (float*)(ws + (1u << 20));
    float* z2     = (float*)(ws + (2u << 20));
    float* w1p    = (float*)(ws + (3u << 20));
    float* w2p    = (float*)(ws + (3u << 20) + (256u << 10));
    float* w2r    = (float*)(ws + (3u << 20) + (512u << 10));

    prep_kernel<<<dim3(288), 256, 0, stream>>>(s1lw, s1rw, s2lw, s2rw, c2w, w1p, w2p, w2r);
    fused_conv_kernel<<<dim3(1024), 256, 0, stream>>>(x, c1w, c1b, w2r, c2b, pooled);
    fc_kernel<<<dim3(1024), 256, 0, stream>>>(pooled, fcw, fcb, mask, z1);
    sage1_kernel<<<dim3(32), 256, 0, stream>>>(z1, s1lw, s1lb, w1p, z2);
    sage2_kernel<<<dim3(32), 256, 0, stream>>>(z2, s2lw, s2lb, w2p, out);
}

// Round 3
// 1699.357 us; speedup vs baseline: 2.9394x; 2.9394x over previous
//
#include <hip/hip_runtime.h>
#include <hip/hip_bf16.h>

// x:[1024,3,32,32] -> conv1(3->64)+relu -> conv2(64->128)+relu -> meanpool
// -> fc(128->256)+b -> *mask -> sage1(256->256)+relu -> sage2(256->128)
// Output [32,32,128] fp32.
//
// Workspace (<4MB):
//  [0,512K)        pooled [1024][128]
//  [1M,2M)         z1 [1024][256]
//  [2M,3M)         z2 [1024][256]
//  [3M,+256K)      w1p [256][256] fp32 = s1rw - s1lw/31
//  [3M+256K,+128K) w2p [128][256] fp32 = s2rw - s2lw/31
//  [3M+512K,+144K) w2b [9][128][64] bf16 conv2 weights, tap-major
//  [3M+768K,+4K)   w1b [64][32] bf16 conv1 weights+bias (k=27 slot = bias)

typedef __attribute__((ext_vector_type(8))) short bfrag;
typedef __attribute__((ext_vector_type(4))) float f32x4;

static __device__ __forceinline__ unsigned short f2bf(float f) {
    union { float f; unsigned u; } v; v.f = f;
    unsigned r = v.u + 0x7fff + ((v.u >> 16) & 1);   // RNE (finite)
    return (unsigned short)(r >> 16);
}

__global__ __launch_bounds__(256) void prep_kernel(
    const float* __restrict__ s1lw, const float* __restrict__ s1rw,
    const float* __restrict__ s2lw, const float* __restrict__ s2rw,
    const float* __restrict__ c2w, const float* __restrict__ c1w,
    const float* __restrict__ c1b,
    float* __restrict__ w1p, float* __restrict__ w2p,
    short* __restrict__ w2b, short* __restrict__ w1b) {
    int i = blockIdx.x * 256 + threadIdx.x;     // grid 288 -> [0, 73728)
    const float inv31 = 1.f / 31.f;
    if (i < 65536) w1p[i] = s1rw[i] - s1lw[i] * inv31;
    if (i < 32768) w2p[i] = s2rw[i] - s2lw[i] * inv31;
    if (i < 73728) {                            // w2b[k][oc][ic] = c2w[oc][ic][k]
        int k = i >> 13, rem = i & 8191, oc = rem >> 6, ic = rem & 63;
        w2b[i] = (short)f2bf(c2w[(oc * 64 + ic) * 9 + k]);
    }
    if (i < 2048) {                             // w1b[oc][k], k=27 -> bias
        int oc = i >> 5, k = i & 31;
        float v = (k < 27) ? c1w[oc * 27 + k] : (k == 27 ? c1b[oc] : 0.f);
        w1b[i] = (short)f2bf(v);
    }
}

// One block per image. conv1 (mfma) -> c1t bf16 -> conv2 (mfma) -> relu+pool.
__global__ __launch_bounds__(256, 2) void fused_conv_kernel(
    const float* __restrict__ x, const short* __restrict__ w1b,
    const short* __restrict__ w2b, const float* __restrict__ b2,
    float* __restrict__ pooled) {
    const int img = blockIdx.x;
    __shared__ short xt[3 * 34 * 34];     // 6936 B  bf16 padded input
    __shared__ short a1t[320 * 32];       // 20480 B im2col band (K=32 incl bias slot)
    __shared__ short c1t[340 * 72];       // 48960 B [row 0..9][col 0..33][ic pad 72]
    __shared__ float psum[128];
    const int t = threadIdx.x;
    const int w = t >> 6, lane = t & 63;
    const int ln15 = lane & 15, q8 = (lane >> 4) * 8;

    // stage input as bf16, zero-padded to 34x34
    const float* xi = x + img * 3072;
    for (int idx = t; idx < 3468; idx += 256) {
        int c = idx / 1156, rem = idx % 1156, yy = rem / 34, xx = rem % 34;
        int y = yy - 1, xc = xx - 1;
        float v = 0.f;
        if ((unsigned)y < 32u && (unsigned)xc < 32u) v = xi[c * 1024 + y * 32 + xc];
        xt[idx] = (short)f2bf(v);
    }
    // zero c1t horizontal pad columns (0 and 33) once; writes only touch 1..32
    for (int i = t; i < 720; i += 256) {
        int r = i / 72, ic = i % 72;
        c1t[(r * 34) * 72 + ic] = 0;
        c1t[(r * 34 + 33) * 72 + ic] = 0;
    }
    if (t < 128) psum[t] = 0.f;

    bfrag b1f[4];                          // conv1 weight frags, hoisted
#pragma unroll
    for (int ot = 0; ot < 4; ++ot)
        b1f[ot] = *(const bfrag*)(w1b + (ot * 16 + ln15) * 32 + q8);
    float b2v[8];
#pragma unroll
    for (int ot = 0; ot < 8; ++ot) b2v[ot] = b2[ot * 16 + ln15];
    float pacc[8];
#pragma unroll
    for (int ot = 0; ot < 8; ++ot) pacc[ot] = 0.f;

    for (int yb = 0; yb < 4; ++yb) {
        const int y0 = yb * 8;
        __syncthreads();                   // prev band readers done
        // ---- im2col: 320 positions = 10 c1t rows x 32 cols ----
        for (int p = t; p < 320; p += 256) {
            int r = p >> 5, xc = p & 31;
            int base = p * 32;
#pragma unroll
            for (int c = 0; c < 3; ++c)
#pragma unroll
                for (int dy = 0; dy < 3; ++dy) {
                    int yy = y0 + r + dy - 1;          // xt row coord
                    yy = yy < 0 ? 0 : (yy > 33 ? 33 : yy);   // clamped rows are zero-pad
#pragma unroll
                    for (int dx = 0; dx < 3; ++dx)
                        a1t[base + c * 9 + dy * 3 + dx] = xt[c * 1156 + yy * 34 + xc + dx];
                }
            a1t[base + 27] = (short)0x3F80;  // 1.0 -> bias slot
            a1t[base + 28] = 0; a1t[base + 29] = 0;
            a1t[base + 30] = 0; a1t[base + 31] = 0;
        }
        __syncthreads();
        // ---- conv1 mfma: wave w -> pos-tiles 5w..5w+4, 4 oc-tiles ----
        {
            f32x4 acc1[5][4];
#pragma unroll
            for (int pt = 0; pt < 5; ++pt)
#pragma unroll
                for (int ot = 0; ot < 4; ++ot)
#pragma unroll
                    for (int rg = 0; rg < 4; ++rg) acc1[pt][ot][rg] = 0.f;
#pragma unroll
            for (int pt = 0; pt < 5; ++pt) {
                bfrag a1f = *(const bfrag*)(&a1t[((w * 5 + pt) * 16 + ln15) * 32 + q8]);
#pragma unroll
                for (int ot = 0; ot < 4; ++ot)
                    acc1[pt][ot] = __builtin_amdgcn_mfma_f32_16x16x32_bf16(
                        a1f, b1f[ot], acc1[pt][ot], 0, 0, 0);
            }
#pragma unroll
            for (int pt = 0; pt < 5; ++pt)
#pragma unroll
                for (int rg = 0; rg < 4; ++rg) {
                    int pos = (w * 5 + pt) * 16 + (lane >> 4) * 4 + rg;
                    int r = pos >> 5, xc = pos & 31;
                    int y = y0 + r - 1;
                    bool valid = (unsigned)y < 32u;    // SAME-pad rows -> 0
#pragma unroll
                    for (int ot = 0; ot < 4; ++ot) {
                        float v = fmaxf(acc1[pt][ot][rg], 0.f);
                        c1t[(r * 34 + xc + 1) * 72 + ot * 16 + ln15] =
                            valid ? (short)f2bf(v) : (short)0;
                    }
                }
        }
        __syncthreads();
        // ---- conv2 mfma: wave w -> band rows 2w,2w+1 (64 pos x 128 oc) ----
        {
            f32x4 acc2[4][8];
#pragma unroll
            for (int pt = 0; pt < 4; ++pt)
#pragma unroll
                for (int ot = 0; ot < 8; ++ot)
#pragma unroll
                    for (int rg = 0; rg < 4; ++rg) acc2[pt][ot][rg] = 0.f;
#pragma unroll
            for (int dydx = 0; dydx < 9; ++dydx) {
                const int dy = dydx / 3, dx = dydx % 3;
#pragma unroll
                for (int kc = 0; kc < 2; ++kc) {
                    bfrag b2f[8];
#pragma unroll
                    for (int ot = 0; ot < 8; ++ot)
                        b2f[ot] = *(const bfrag*)(
                            w2b + (dydx * 128 + ot * 16 + ln15) * 64 + kc * 32 + q8);
                    bfrag a2f[4];
#pragma unroll
                    for (int pt = 0; pt < 4; ++pt) {
                        int r = 2 * w + (pt >> 1);
                        int xc = ((pt & 1) << 4) + ln15;
                        a2f[pt] = *(const bfrag*)(
                            &c1t[((r + dy) * 34 + xc + dx) * 72 + kc * 32 + q8]);
                    }
#pragma unroll
                    for (int pt = 0; pt < 4; ++pt)
#pragma unroll
                        for (int ot = 0; ot < 8; ++ot)
                            acc2[pt][ot] = __builtin_amdgcn_mfma_f32_16x16x32_bf16(
                                a2f[pt], b2f[ot], acc2[pt][ot], 0, 0, 0);
                }
            }
            // bias + relu + pool partial
#pragma unroll
            for (int ot = 0; ot < 8; ++ot) {
                float s = 0.f;
#pragma unroll
                for (int pt = 0; pt < 4; ++pt)
#pragma unroll
                    for (int rg = 0; rg < 4; ++rg)
                        s += fmaxf(acc2[pt][ot][rg] + b2v[ot], 0.f);
                pacc[ot] += s;
            }
        }
    }
    // reduce across the 4 row-groups (lanes 16 apart), then block-level
#pragma unroll
    for (int ot = 0; ot < 8; ++ot) {
        float v = pacc[ot];
        v += __shfl_xor(v, 16, 64);
        v += __shfl_xor(v, 32, 64);
        if (lane < 16) atomicAdd(&psum[ot * 16 + ln15], v);
    }
    __syncthreads();
    if (t < 128) pooled[img * 128 + t] = psum[t] * (1.f / 1024.f);
}

__global__ __launch_bounds__(256) void fc_kernel(
    const float* __restrict__ pooled, const float* __restrict__ fw,
    const float* __restrict__ fb, const float* __restrict__ mask,
    float* __restrict__ z1) {
    const int img = blockIdx.x;
    __shared__ float m[128];
    const int t = threadIdx.x;
    if (t < 128) m[t] = pooled[img * 128 + t];
    __syncthreads();
    float acc = fb[t];
#pragma unroll 4
    for (int c = 0; c < 128; ++c) acc = fmaf(m[c], fw[t * 128 + c], acc);
    z1[img * 256 + t] = acc * mask[img];
}

__global__ __launch_bounds__(256) void sage1_kernel(
    const float* __restrict__ z1, const float* __restrict__ lw,
    const float* __restrict__ lb, const float* __restrict__ w1p,
    float* __restrict__ z2) {
    const int bb = blockIdx.x;
    __shared__ float h[32 * 256];
    __shared__ float sl[256];
    const int t = threadIdx.x;
    const float* zb = z1 + bb * 8192;
    for (int idx = t; idx < 8192; idx += 256) h[idx] = zb[idx];
    __syncthreads();
    float s = 0.f;
#pragma unroll
    for (int n = 0; n < 32; ++n) s += h[n * 256 + t];
    sl[t] = s * (1.f / 31.f);
    __syncthreads();
    float c = lb[t];
#pragma unroll 4
    for (int d = 0; d < 256; ++d) c = fmaf(sl[d], lw[t * 256 + d], c);
    for (int i = 0; i < 32; ++i) {
        float a = c;
#pragma unroll 4
        for (int d = 0; d < 256; ++d) a = fmaf(h[i * 256 + d], w1p[t * 256 + d], a);
        z2[(bb * 32 + i) * 256 + t] = fmaxf(a, 0.f);
    }
}

__global__ __launch_bounds__(256) void sage2_kernel(
    const float* __restrict__ z2, const float* __restrict__ lw,
    const float* __restrict__ lb, const float* __restrict__ w2p,
    float* __restrict__ out) {
    const int bb = blockIdx.x;
    __shared__ float h[32 * 256];
    __shared__ float sl[256];
    const int t = threadIdx.x;
    const float* zb = z2 + bb * 8192;
    for (int idx = t; idx < 8192; idx += 256) h[idx] = zb[idx];
    __syncthreads();
    float s = 0.f;
#pragma unroll
    for (int n = 0; n < 32; ++n) s += h[n * 256 + t];
    sl[t] = s * (1.f / 31.f);
    __syncthreads();
    const int o = t & 127, ihalf = t >> 7;
    float c = lb[o];
#pragma unroll 4
    for (int d = 0; d < 256; ++d) c = fmaf(sl[d], lw[o * 256 + d], c);
    for (int i = ihalf * 16; i < ihalf * 16 + 16; ++i) {
        float a = c;
#pragma unroll 4
        for (int d = 0; d < 256; ++d) a = fmaf(h[i * 256 + d], w2p[o * 256 + d], a);
        out[(bb * 32 + i) * 128 + o] = a;
    }
}

extern "C" void kernel_launch(void* const* d_in, const int* in_sizes, int n_in,
                              void* d_out, int out_size, void* d_ws, size_t ws_size,
                              hipStream_t stream) {
    const float* x    = (const float*)d_in[0];
    const float* mask = (const float*)d_in[1];
    const float* c1w  = (const float*)d_in[2];
    const float* c1b  = (const float*)d_in[3];
    const float* c2w  = (const float*)d_in[4];
    const float* c2b  = (const float*)d_in[5];
    const float* fcw  = (const float*)d_in[6];
    const float* fcb  = (const float*)d_in[7];
    const float* s1lw = (const float*)d_in[8];
    const float* s1lb = (const float*)d_in[9];
    const float* s1rw = (const float*)d_in[10];
    const float* s2lw = (const float*)d_in[11];
    const float* s2lb = (const float*)d_in[12];
    const float* s2rw = (const float*)d_in[13];
    float* out = (float*)d_out;

    char* ws = (char*)d_ws;
    float* pooled = (float*)(ws);
    float* z1     = (float*)(ws + (1u << 20));
    float* z2     = (float*)(ws + (2u << 20));
    float* w1p    = (float*)(ws + (3u << 20));
    float* w2p    = (float*)(ws + (3u << 20) + (256u << 10));
    short* w2b    = (short*)(ws + (3u << 20) + (512u << 10));
    short* w1b    = (short*)(ws + (3u << 20) + (768u << 10));

    prep_kernel<<<dim3(288), 256, 0, stream>>>(s1lw, s1rw, s2lw, s2rw, c2w, c1w, c1b,
                                               w1p, w2p, w2b, w1b);
    fused_conv_kernel<<<dim3(1024), 256, 0, stream>>>(x, w1b, w2b, c2b, pooled);
    fc_kernel<<<dim3(1024), 256, 0, stream>>>(pooled, fcw, fcb, mask, z1);
    sage1_kernel<<<dim3(32), 256, 0, stream>>>(z1, s1lw, s1lb, w1p, z2);
    sage2_kernel<<<dim3(32), 256, 0, stream>>>(z2, s2lw, s2lb, w2p, out);
}

// Round 4
// 1426.444 us; speedup vs baseline: 3.5018x; 1.1913x over previous
//
#include <hip/hip_runtime.h>
#include <hip/hip_bf16.h>

// x:[1024,3,32,32] -> conv1(3->64)+relu -> conv2(64->128)+relu -> meanpool
// -> fc(128->256)+b -> *mask -> sage1(256->256)+relu -> sage2(256->128)
// Output [32,32,128] fp32.
//
// Workspace (~3.6MB):
//  [0,512K)        pooled [1024][128]
//  [512K,1536K)    z1 [1024][256]
//  [1536K,2560K)   z2 [1024][256]
//  [2560K,2816K)   l1T  [256][256] fp32  = s1lw^T
//  [2816K,3072K)   w1pT [256][256] fp32  = (s1rw - s1lw/31)^T
//  [3072K,3200K)   l2T  [256][128] fp32  = s2lw^T
//  [3200K,3328K)   w2pT [256][128] fp32  = (s2rw - s2lw/31)^T
//  [3328K,3456K)   fwT  [128][256] fp32  = fc_w^T
//  [3456K,3600K)   w2b  [9][128][64] bf16 conv2 weights, tap-major
//  [3600K,3604K)   w1b  [64][32] bf16 conv1 weights+bias (k=27 slot = bias)

typedef __attribute__((ext_vector_type(8))) short bfrag;
typedef __attribute__((ext_vector_type(4))) float f32x4;

static __device__ __forceinline__ unsigned short f2bf(float f) {
    union { float f; unsigned u; } v; v.f = f;
    unsigned r = v.u + 0x7fff + ((v.u >> 16) & 1);   // RNE (finite)
    return (unsigned short)(r >> 16);
}

__global__ __launch_bounds__(256) void prep_kernel(
    const float* __restrict__ s1lw, const float* __restrict__ s1rw,
    const float* __restrict__ s2lw, const float* __restrict__ s2rw,
    const float* __restrict__ c2w, const float* __restrict__ c1w,
    const float* __restrict__ c1b, const float* __restrict__ fcw,
    float* __restrict__ l1T, float* __restrict__ w1pT,
    float* __restrict__ l2T, float* __restrict__ w2pT,
    float* __restrict__ fwT,
    short* __restrict__ w2b, short* __restrict__ w1b) {
    int i = blockIdx.x * 256 + threadIdx.x;     // grid 288 -> [0, 73728)
    const float inv31 = 1.f / 31.f;
    if (i < 65536) {                            // [d][o] transposes, 256x256
        int d = i >> 8, o = i & 255;
        float lw = s1lw[o * 256 + d];
        l1T[i]  = lw;
        w1pT[i] = s1rw[o * 256 + d] - lw * inv31;
    }
    if (i < 32768) {                            // [d][o] 256x128 + fwT 128x256
        int d = i >> 7, o = i & 127;
        float lw = s2lw[o * 256 + d];
        l2T[i]  = lw;
        w2pT[i] = s2rw[o * 256 + d] - lw * inv31;
        int c = i >> 8, o2 = i & 255;
        fwT[i] = fcw[o2 * 128 + c];
    }
    if (i < 73728) {                            // w2b[k][oc][ic] = c2w[oc][ic][k]
        int k = i >> 13, rem = i & 8191, oc = rem >> 6, ic = rem & 63;
        w2b[i] = (short)f2bf(c2w[(oc * 64 + ic) * 9 + k]);
    }
    if (i < 2048) {                             // w1b[oc][k], k=27 -> bias
        int oc = i >> 5, k = i & 31;
        float v = (k < 27) ? c1w[oc * 27 + k] : (k == 27 ? c1b[oc] : 0.f);
        w1b[i] = (short)f2bf(v);
    }
}

// One block per image. conv1 (mfma) -> c1t bf16 -> conv2 (mfma) -> relu+pool.
__global__ __launch_bounds__(256, 2) void fused_conv_kernel(
    const float* __restrict__ x, const short* __restrict__ w1b,
    const short* __restrict__ w2b, const float* __restrict__ b2,
    float* __restrict__ pooled) {
    const int img = blockIdx.x;
    __shared__ short xt[3 * 34 * 34];     // 6936 B  bf16 padded input
    __shared__ short a1t[320 * 32];       // 20480 B im2col band (K=32 incl bias)
    __shared__ short c1t[340 * 72];       // 48960 B [row 0..9][col 0..33][ic pad 72]
    __shared__ float psum[128];
    const int t = threadIdx.x;
    const int w = t >> 6, lane = t & 63;
    const int ln15 = lane & 15, q8 = (lane >> 4) * 8;

    const float* xi = x + img * 3072;
    for (int idx = t; idx < 3468; idx += 256) {
        int c = idx / 1156, rem = idx % 1156, yy = rem / 34, xx = rem % 34;
        int y = yy - 1, xc = xx - 1;
        float v = 0.f;
        if ((unsigned)y < 32u && (unsigned)xc < 32u) v = xi[c * 1024 + y * 32 + xc];
        xt[idx] = (short)f2bf(v);
    }
    for (int i = t; i < 720; i += 256) {       // zero c1t pad columns 0 and 33
        int r = i / 72, ic = i % 72;
        c1t[(r * 34) * 72 + ic] = 0;
        c1t[(r * 34 + 33) * 72 + ic] = 0;
    }
    if (t < 128) psum[t] = 0.f;

    float b2v[8];
#pragma unroll
    for (int ot = 0; ot < 8; ++ot) b2v[ot] = b2[ot * 16 + ln15];
    float pacc[8];
#pragma unroll
    for (int ot = 0; ot < 8; ++ot) pacc[ot] = 0.f;

    for (int yb = 0; yb < 4; ++yb) {
        const int y0 = yb * 8;
        __syncthreads();                   // prev band's c1t readers done
        // ---- im2col: 320 positions = 10 c1t rows x 32 cols ----
        for (int p = t; p < 320; p += 256) {
            int r = p >> 5, xc = p & 31;
            int base = p * 32;
#pragma unroll
            for (int c = 0; c < 3; ++c)
#pragma unroll
                for (int dy = 0; dy < 3; ++dy) {
                    int yy = y0 + r + dy - 1;
                    yy = yy < 0 ? 0 : (yy > 33 ? 33 : yy);   // clamped rows zero-pad
#pragma unroll
                    for (int dx = 0; dx < 3; ++dx)
                        a1t[base + c * 9 + dy * 3 + dx] = xt[c * 1156 + yy * 34 + xc + dx];
                }
            a1t[base + 27] = (short)0x3F80;  // 1.0 -> bias slot
            a1t[base + 28] = 0; a1t[base + 29] = 0;
            a1t[base + 30] = 0; a1t[base + 31] = 0;
        }
        __syncthreads();
        // ---- conv1 mfma: low register footprint (16 acc regs live) ----
        {
            bfrag b1f[4];
#pragma unroll
            for (int ot = 0; ot < 4; ++ot)
                b1f[ot] = *(const bfrag*)(w1b + (ot * 16 + ln15) * 32 + q8);
#pragma unroll
            for (int pt = 0; pt < 5; ++pt) {
                bfrag a1f = *(const bfrag*)(&a1t[((w * 5 + pt) * 16 + ln15) * 32 + q8]);
                f32x4 acc1[4];
#pragma unroll
                for (int ot = 0; ot < 4; ++ot) {
#pragma unroll
                    for (int rg = 0; rg < 4; ++rg) acc1[ot][rg] = 0.f;
                    acc1[ot] = __builtin_amdgcn_mfma_f32_16x16x32_bf16(
                        a1f, b1f[ot], acc1[ot], 0, 0, 0);
                }
#pragma unroll
                for (int rg = 0; rg < 4; ++rg) {
                    int pos = (w * 5 + pt) * 16 + (lane >> 4) * 4 + rg;
                    int r = pos >> 5, xc = pos & 31;
                    int y = y0 + r - 1;
                    bool valid = (unsigned)y < 32u;    // SAME-pad rows -> 0
#pragma unroll
                    for (int ot = 0; ot < 4; ++ot) {
                        float v = fmaxf(acc1[ot][rg], 0.f);
                        c1t[(r * 34 + xc + 1) * 72 + ot * 16 + ln15] =
                            valid ? (short)f2bf(v) : (short)0;
                    }
                }
            }
        }
        __syncthreads();
        // ---- conv2 mfma: wave w -> band rows 2w,2w+1 (64 pos x 128 oc) ----
        {
            f32x4 acc2[4][8];
#pragma unroll
            for (int pt = 0; pt < 4; ++pt)
#pragma unroll
                for (int ot = 0; ot < 8; ++ot)
#pragma unroll
                    for (int rg = 0; rg < 4; ++rg) acc2[pt][ot][rg] = 0.f;
#pragma unroll
            for (int dydx = 0; dydx < 9; ++dydx) {
                const int dy = dydx / 3, dx = dydx % 3;
#pragma unroll
                for (int kc = 0; kc < 2; ++kc) {
#pragma unroll
                    for (int g = 0; g < 2; ++g) {      // oc groups of 4 tiles
                        bfrag b2f[4];
#pragma unroll
                        for (int o4 = 0; o4 < 4; ++o4)
                            b2f[o4] = *(const bfrag*)(
                                w2b + (dydx * 128 + (g * 4 + o4) * 16 + ln15) * 64
                                    + kc * 32 + q8);
#pragma unroll
                        for (int pt = 0; pt < 4; ++pt) {
                            int r = 2 * w + (pt >> 1);
                            int xc = ((pt & 1) << 4) + ln15;
                            bfrag a2f = *(const bfrag*)(
                                &c1t[((r + dy) * 34 + xc + dx) * 72 + kc * 32 + q8]);
#pragma unroll
                            for (int o4 = 0; o4 < 4; ++o4)
                                acc2[pt][g * 4 + o4] = __builtin_amdgcn_mfma_f32_16x16x32_bf16(
                                    a2f, b2f[o4], acc2[pt][g * 4 + o4], 0, 0, 0);
                        }
                    }
                }
            }
#pragma unroll
            for (int ot = 0; ot < 8; ++ot) {
                float s = 0.f;
#pragma unroll
                for (int pt = 0; pt < 4; ++pt)
#pragma unroll
                    for (int rg = 0; rg < 4; ++rg)
                        s += fmaxf(acc2[pt][ot][rg] + b2v[ot], 0.f);
                pacc[ot] += s;
            }
        }
    }
#pragma unroll
    for (int ot = 0; ot < 8; ++ot) {
        float v = pacc[ot];
        v += __shfl_xor(v, 16, 64);
        v += __shfl_xor(v, 32, 64);
        if (lane < 16) atomicAdd(&psum[ot * 16 + ln15], v);
    }
    __syncthreads();
    if (t < 128) pooled[img * 128 + t] = psum[t] * (1.f / 1024.f);
}

__global__ __launch_bounds__(256) void fc_kernel(
    const float* __restrict__ pooled, const float* __restrict__ fwT,
    const float* __restrict__ fb, const float* __restrict__ mask,
    float* __restrict__ z1) {
    const int img = blockIdx.x;
    __shared__ float m[128];
    const int t = threadIdx.x;
    if (t < 128) m[t] = pooled[img * 128 + t];
    __syncthreads();
    float acc = fb[t];
#pragma unroll 4
    for (int c = 0; c < 128; ++c) acc = fmaf(m[c], fwT[c * 256 + t], acc);  // coalesced
    z1[img * 256 + t] = acc * mask[img];
}

// sage1+relu: thread t = output o; 32 node accumulators; coalesced weights.
__global__ __launch_bounds__(256) void sage1_kernel(
    const float* __restrict__ z1, const float* __restrict__ l1T,
    const float* __restrict__ lb, const float* __restrict__ w1pT,
    float* __restrict__ z2) {
    const int bb = blockIdx.x;
    __shared__ float h[32 * 256];
    __shared__ float sl[256];
    const int t = threadIdx.x;
    const float* zb = z1 + bb * 8192;
    for (int idx = t; idx < 8192; idx += 256) h[idx] = zb[idx];
    __syncthreads();
    float s = 0.f;
#pragma unroll
    for (int n = 0; n < 32; ++n) s += h[n * 256 + t];
    sl[t] = s * (1.f / 31.f);
    __syncthreads();
    float c = lb[t];
#pragma unroll 4
    for (int d = 0; d < 256; ++d) c = fmaf(sl[d], l1T[d * 256 + t], c);
    float acc[32];
#pragma unroll
    for (int i = 0; i < 32; ++i) acc[i] = c;
    for (int d0 = 0; d0 < 256; d0 += 4) {
        float wv0 = w1pT[(d0 + 0) * 256 + t];
        float wv1 = w1pT[(d0 + 1) * 256 + t];
        float wv2 = w1pT[(d0 + 2) * 256 + t];
        float wv3 = w1pT[(d0 + 3) * 256 + t];
#pragma unroll
        for (int i = 0; i < 32; ++i) {
            f32x4 hv = *(const f32x4*)&h[i * 256 + d0];   // LDS broadcast b128
            acc[i] = fmaf(hv[0], wv0, acc[i]);
            acc[i] = fmaf(hv[1], wv1, acc[i]);
            acc[i] = fmaf(hv[2], wv2, acc[i]);
            acc[i] = fmaf(hv[3], wv3, acc[i]);
        }
    }
    for (int i = 0; i < 32; ++i)
        z2[(bb * 32 + i) * 256 + t] = fmaxf(acc[i], 0.f);
}

// sage2: o = t&127, node-half = t>>7; 16 accumulators.
__global__ __launch_bounds__(256) void sage2_kernel(
    const float* __restrict__ z2, const float* __restrict__ l2T,
    const float* __restrict__ lb, const float* __restrict__ w2pT,
    float* __restrict__ out) {
    const int bb = blockIdx.x;
    __shared__ float h[32 * 256];
    __shared__ float sl[256];
    const int t = threadIdx.x;
    const float* zb = z2 + bb * 8192;
    for (int idx = t; idx < 8192; idx += 256) h[idx] = zb[idx];
    __syncthreads();
    float s = 0.f;
#pragma unroll
    for (int n = 0; n < 32; ++n) s += h[n * 256 + t];
    sl[t] = s * (1.f / 31.f);
    __syncthreads();
    const int o = t & 127, half = t >> 7;
    float c = lb[o];
#pragma unroll 4
    for (int d = 0; d < 256; ++d) c = fmaf(sl[d], l2T[d * 128 + o], c);
    float acc[16];
#pragma unroll
    for (int i = 0; i < 16; ++i) acc[i] = c;
    for (int d0 = 0; d0 < 256; d0 += 4) {
        float wv0 = w2pT[(d0 + 0) * 128 + o];
        float wv1 = w2pT[(d0 + 1) * 128 + o];
        float wv2 = w2pT[(d0 + 2) * 128 + o];
        float wv3 = w2pT[(d0 + 3) * 128 + o];
#pragma unroll
        for (int ii = 0; ii < 16; ++ii) {
            f32x4 hv = *(const f32x4*)&h[(half * 16 + ii) * 256 + d0];
            acc[ii] = fmaf(hv[0], wv0, acc[ii]);
            acc[ii] = fmaf(hv[1], wv1, acc[ii]);
            acc[ii] = fmaf(hv[2], wv2, acc[ii]);
            acc[ii] = fmaf(hv[3], wv3, acc[ii]);
        }
    }
    for (int ii = 0; ii < 16; ++ii)
        out[(bb * 32 + half * 16 + ii) * 128 + o] = acc[ii];
}

extern "C" void kernel_launch(void* const* d_in, const int* in_sizes, int n_in,
                              void* d_out, int out_size, void* d_ws, size_t ws_size,
                              hipStream_t stream) {
    const float* x    = (const float*)d_in[0];
    const float* mask = (const float*)d_in[1];
    const float* c1w  = (const float*)d_in[2];
    const float* c1b  = (const float*)d_in[3];
    const float* c2w  = (const float*)d_in[4];
    const float* c2b  = (const float*)d_in[5];
    const float* fcw  = (const float*)d_in[6];
    const float* fcb  = (const float*)d_in[7];
    const float* s1lw = (const float*)d_in[8];
    const float* s1lb = (const float*)d_in[9];
    const float* s1rw = (const float*)d_in[10];
    const float* s2lw = (const float*)d_in[11];
    const float* s2lb = (const float*)d_in[12];
    const float* s2rw = (const float*)d_in[13];
    float* out = (float*)d_out;

    char* ws = (char*)d_ws;
    float* pooled = (float*)(ws);
    float* z1     = (float*)(ws + (512u  << 10));
    float* z2     = (float*)(ws + (1536u << 10));
    float* l1T    = (float*)(ws + (2560u << 10));
    float* w1pT   = (float*)(ws + (2816u << 10));
    float* l2T    = (float*)(ws + (3072u << 10));
    float* w2pT   = (float*)(ws + (3200u << 10));
    float* fwT    = (float*)(ws + (3328u << 10));
    short* w2b    = (short*)(ws + (3456u << 10));
    short* w1b    = (short*)(ws + (3600u << 10));

    prep_kernel<<<dim3(288), 256, 0, stream>>>(s1lw, s1rw, s2lw, s2rw, c2w, c1w, c1b,
                                               fcw, l1T, w1pT, l2T, w2pT, fwT, w2b, w1b);
    fused_conv_kernel<<<dim3(1024), 256, 0, stream>>>(x, w1b, w2b, c2b, pooled);
    fc_kernel<<<dim3(1024), 256, 0, stream>>>(pooled, fwT, fcb, mask, z1);
    sage1_kernel<<<dim3(32), 256, 0, stream>>>(z1, l1T, s1lb, w1pT, z2);
    sage2_kernel<<<dim3(32), 256, 0, stream>>>(z2, l2T, s2lb, w2pT, out);
}

// Round 5
// 469.240 us; speedup vs baseline: 10.6452x; 3.0399x over previous
//
#include <hip/hip_runtime.h>
#include <hip/hip_bf16.h>

// x:[1024,3,32,32] -> conv1(3->64)+relu -> conv2(64->128)+relu -> meanpool
// -> fc(128->256)+b -> *mask -> sage1(256->256)+relu -> sage2(256->128)
// Output [32,32,128] fp32.
//
// Workspace (~3.6MB):
//  [0,512K)        pooled [1024][128]
//  [512K,1536K)    z1 [1024][256]
//  [1536K,2560K)   z2 [1024][256]
//  [2560K,2816K)   l1T  [256][256] fp32  = s1lw^T
//  [2816K,3072K)   w1pT [256][256] fp32  = (s1rw - s1lw/31)^T
//  [3072K,3200K)   l2T  [256][128] fp32  = s2lw^T
//  [3200K,3328K)   w2pT [256][128] fp32  = (s2rw - s2lw/31)^T
//  [3328K,3456K)   fwT  [128][256] fp32  = fc_w^T
//  [3456K,3600K)   w2b  [9][128][64] bf16 conv2 weights, tap-major
//  [3600K,3604K)   w1b  [64][32] bf16 conv1 weights+bias (k=27 slot = bias)

typedef __attribute__((ext_vector_type(8))) short bfrag;
typedef __attribute__((ext_vector_type(4))) float f32x4;

static __device__ __forceinline__ unsigned short f2bf(float f) {
    union { float f; unsigned u; } v; v.f = f;
    unsigned r = v.u + 0x7fff + ((v.u >> 16) & 1);   // RNE (finite)
    return (unsigned short)(r >> 16);
}

__global__ __launch_bounds__(256) void prep_kernel(
    const float* __restrict__ s1lw, const float* __restrict__ s1rw,
    const float* __restrict__ s2lw, const float* __restrict__ s2rw,
    const float* __restrict__ c2w, const float* __restrict__ c1w,
    const float* __restrict__ c1b, const float* __restrict__ fcw,
    float* __restrict__ l1T, float* __restrict__ w1pT,
    float* __restrict__ l2T, float* __restrict__ w2pT,
    float* __restrict__ fwT,
    short* __restrict__ w2b, short* __restrict__ w1b) {
    int i = blockIdx.x * 256 + threadIdx.x;     // grid 288 -> [0, 73728)
    const float inv31 = 1.f / 31.f;
    if (i < 65536) {                            // [d][o] transposes, 256x256
        int d = i >> 8, o = i & 255;
        float lw = s1lw[o * 256 + d];
        l1T[i]  = lw;
        w1pT[i] = s1rw[o * 256 + d] - lw * inv31;
    }
    if (i < 32768) {                            // [d][o] 256x128 + fwT 128x256
        int d = i >> 7, o = i & 127;
        float lw = s2lw[o * 256 + d];
        l2T[i]  = lw;
        w2pT[i] = s2rw[o * 256 + d] - lw * inv31;
        int c = i >> 8, o2 = i & 255;
        fwT[i] = fcw[o2 * 128 + c];
    }
    if (i < 73728) {                            // w2b[k][oc][ic] = c2w[oc][ic][k]
        int k = i >> 13, rem = i & 8191, oc = rem >> 6, ic = rem & 63;
        w2b[i] = (short)f2bf(c2w[(oc * 64 + ic) * 9 + k]);
    }
    if (i < 2048) {                             // w1b[oc][k], k=27 -> bias
        int oc = i >> 5, k = i & 31;
        float v = (k < 27) ? c1w[oc * 27 + k] : (k == 27 ? c1b[oc] : 0.f);
        w1b[i] = (short)f2bf(v);
    }
}

// One block per image. conv1 (mfma) -> c1t bf16 -> conv2 (mfma) -> relu+pool.
__global__ __launch_bounds__(256, 2) void fused_conv_kernel(
    const float* __restrict__ x, const short* __restrict__ w1b,
    const short* __restrict__ w2b, const float* __restrict__ b2,
    float* __restrict__ pooled) {
    const int img = blockIdx.x;
    __shared__ short xt[3 * 34 * 34];     // 6936 B  bf16 padded input
    __shared__ short a1t[320 * 32];       // 20480 B im2col band (K=32 incl bias)
    __shared__ short c1t[340 * 72];       // 48960 B [row 0..9][col 0..33][ic pad 72]
    __shared__ float psum[128];
    const int t = threadIdx.x;
    const int w = t >> 6, lane = t & 63;
    const int ln15 = lane & 15, q8 = (lane >> 4) * 8;

    const float* xi = x + img * 3072;
    for (int idx = t; idx < 3468; idx += 256) {
        int c = idx / 1156, rem = idx % 1156, yy = rem / 34, xx = rem % 34;
        int y = yy - 1, xc = xx - 1;
        float v = 0.f;
        if ((unsigned)y < 32u && (unsigned)xc < 32u) v = xi[c * 1024 + y * 32 + xc];
        xt[idx] = (short)f2bf(v);
    }
    for (int i = t; i < 720; i += 256) {       // zero c1t pad columns 0 and 33
        int r = i / 72, ic = i % 72;
        c1t[(r * 34) * 72 + ic] = 0;
        c1t[(r * 34 + 33) * 72 + ic] = 0;
    }
    if (t < 128) psum[t] = 0.f;

    float b2v[8];
#pragma unroll
    for (int ot = 0; ot < 8; ++ot) b2v[ot] = b2[ot * 16 + ln15];
    float pacc[8];
#pragma unroll
    for (int ot = 0; ot < 8; ++ot) pacc[ot] = 0.f;

    for (int yb = 0; yb < 4; ++yb) {
        const int y0 = yb * 8;
        __syncthreads();                   // prev band's c1t readers done
        // ---- im2col: 320 positions = 10 c1t rows x 32 cols ----
        for (int p = t; p < 320; p += 256) {
            int r = p >> 5, xc = p & 31;
            int base = p * 32;
#pragma unroll
            for (int c = 0; c < 3; ++c)
#pragma unroll
                for (int dy = 0; dy < 3; ++dy) {
                    int yy = y0 + r + dy - 1;
                    yy = yy < 0 ? 0 : (yy > 33 ? 33 : yy);   // clamped rows zero-pad
#pragma unroll
                    for (int dx = 0; dx < 3; ++dx)
                        a1t[base + c * 9 + dy * 3 + dx] = xt[c * 1156 + yy * 34 + xc + dx];
                }
            a1t[base + 27] = (short)0x3F80;  // 1.0 -> bias slot
            a1t[base + 28] = 0; a1t[base + 29] = 0;
            a1t[base + 30] = 0; a1t[base + 31] = 0;
        }
        __syncthreads();
        // ---- conv1 mfma (pt loop NOT unrolled: cap live regs) ----
        {
            bfrag b1f[4];
#pragma unroll
            for (int ot = 0; ot < 4; ++ot)
                b1f[ot] = *(const bfrag*)(w1b + (ot * 16 + ln15) * 32 + q8);
#pragma unroll 1
            for (int pt = 0; pt < 5; ++pt) {
                bfrag a1f = *(const bfrag*)(&a1t[((w * 5 + pt) * 16 + ln15) * 32 + q8]);
                f32x4 acc1[4];
#pragma unroll
                for (int ot = 0; ot < 4; ++ot) {
#pragma unroll
                    for (int rg = 0; rg < 4; ++rg) acc1[ot][rg] = 0.f;
                    acc1[ot] = __builtin_amdgcn_mfma_f32_16x16x32_bf16(
                        a1f, b1f[ot], acc1[ot], 0, 0, 0);
                }
#pragma unroll
                for (int rg = 0; rg < 4; ++rg) {
                    int pos = (w * 5 + pt) * 16 + (lane >> 4) * 4 + rg;
                    int r = pos >> 5, xc = pos & 31;
                    int y = y0 + r - 1;
                    bool valid = (unsigned)y < 32u;    // SAME-pad rows -> 0
#pragma unroll
                    for (int ot = 0; ot < 4; ++ot) {
                        float v = fmaxf(acc1[ot][rg], 0.f);
                        c1t[(r * 34 + xc + 1) * 72 + ot * 16 + ln15] =
                            valid ? (short)f2bf(v) : (short)0;
                    }
                }
            }
        }
        __syncthreads();
        // ---- conv2 mfma: wave w -> band rows 2w,2w+1 (64 pos x 128 oc).
        //      Tap loop NOT unrolled: prevents cross-tap load hoisting (spills). ----
        {
            f32x4 acc2[4][8];
#pragma unroll
            for (int pt = 0; pt < 4; ++pt)
#pragma unroll
                for (int ot = 0; ot < 8; ++ot)
#pragma unroll
                    for (int rg = 0; rg < 4; ++rg) acc2[pt][ot][rg] = 0.f;
#pragma unroll 1
            for (int dydx = 0; dydx < 9; ++dydx) {
                const int dy = dydx / 3, dx = dydx - dy * 3;
                const short* wbase = w2b + dydx * 8192;
#pragma unroll
                for (int kc = 0; kc < 2; ++kc) {
#pragma unroll
                    for (int g = 0; g < 2; ++g) {      // oc groups of 4 tiles
                        bfrag b2f[4];
#pragma unroll
                        for (int o4 = 0; o4 < 4; ++o4)
                            b2f[o4] = *(const bfrag*)(
                                wbase + ((g * 4 + o4) * 16 + ln15) * 64 + kc * 32 + q8);
#pragma unroll
                        for (int pt = 0; pt < 4; ++pt) {
                            int r = 2 * w + (pt >> 1);
                            int xc = ((pt & 1) << 4) + ln15;
                            bfrag a2f = *(const bfrag*)(
                                &c1t[((r + dy) * 34 + xc + dx) * 72 + kc * 32 + q8]);
#pragma unroll
                            for (int o4 = 0; o4 < 4; ++o4)
                                acc2[pt][g * 4 + o4] = __builtin_amdgcn_mfma_f32_16x16x32_bf16(
                                    a2f, b2f[o4], acc2[pt][g * 4 + o4], 0, 0, 0);
                        }
                    }
                }
            }
#pragma unroll
            for (int ot = 0; ot < 8; ++ot) {
                float s = 0.f;
#pragma unroll
                for (int pt = 0; pt < 4; ++pt)
#pragma unroll
                    for (int rg = 0; rg < 4; ++rg)
                        s += fmaxf(acc2[pt][ot][rg] + b2v[ot], 0.f);
                pacc[ot] += s;
            }
        }
    }
#pragma unroll
    for (int ot = 0; ot < 8; ++ot) {
        float v = pacc[ot];
        v += __shfl_xor(v, 16, 64);
        v += __shfl_xor(v, 32, 64);
        if (lane < 16) atomicAdd(&psum[ot * 16 + ln15], v);
    }
    __syncthreads();
    if (t < 128) pooled[img * 128 + t] = psum[t] * (1.f / 1024.f);
}

__global__ __launch_bounds__(256) void fc_kernel(
    const float* __restrict__ pooled, const float* __restrict__ fwT,
    const float* __restrict__ fb, const float* __restrict__ mask,
    float* __restrict__ z1) {
    const int img = blockIdx.x;
    __shared__ float m[128];
    const int t = threadIdx.x;
    if (t < 128) m[t] = pooled[img * 128 + t];
    __syncthreads();
    float acc = fb[t];
#pragma unroll 4
    for (int c = 0; c < 128; ++c) acc = fmaf(m[c], fwT[c * 256 + t], acc);  // coalesced
    z1[img * 256 + t] = acc * mask[img];
}

// sage1+relu: grid 128 = (bb, chunk of 8 nodes); thread t = output o.
__global__ __launch_bounds__(256) void sage1_kernel(
    const float* __restrict__ z1, const float* __restrict__ l1T,
    const float* __restrict__ lb, const float* __restrict__ w1pT,
    float* __restrict__ z2) {
    const int bb = blockIdx.x >> 2, chunk = blockIdx.x & 3;
    __shared__ float h[32 * 256];
    __shared__ float sl[256];
    const int t = threadIdx.x;
    const float* zb = z1 + bb * 8192;
    for (int idx = t; idx < 8192; idx += 256) h[idx] = zb[idx];
    __syncthreads();
    float s = 0.f;
#pragma unroll
    for (int n = 0; n < 32; ++n) s += h[n * 256 + t];
    sl[t] = s * (1.f / 31.f);
    __syncthreads();
    float c = lb[t];
#pragma unroll 4
    for (int d = 0; d < 256; ++d) c = fmaf(sl[d], l1T[d * 256 + t], c);
    float acc[8];
#pragma unroll
    for (int i = 0; i < 8; ++i) acc[i] = c;
    for (int d0 = 0; d0 < 256; d0 += 4) {
        float wv0 = w1pT[(d0 + 0) * 256 + t];
        float wv1 = w1pT[(d0 + 1) * 256 + t];
        float wv2 = w1pT[(d0 + 2) * 256 + t];
        float wv3 = w1pT[(d0 + 3) * 256 + t];
#pragma unroll
        for (int i = 0; i < 8; ++i) {
            f32x4 hv = *(const f32x4*)&h[(chunk * 8 + i) * 256 + d0];  // LDS broadcast
            acc[i] = fmaf(hv[0], wv0, acc[i]);
            acc[i] = fmaf(hv[1], wv1, acc[i]);
            acc[i] = fmaf(hv[2], wv2, acc[i]);
            acc[i] = fmaf(hv[3], wv3, acc[i]);
        }
    }
    for (int i = 0; i < 8; ++i)
        z2[(bb * 32 + chunk * 8 + i) * 256 + t] = fmaxf(acc[i], 0.f);
}

// sage2: grid 128 = (bb, chunk of 8 nodes); o = t&127, half = t>>7 (4 nodes each).
__global__ __launch_bounds__(256) void sage2_kernel(
    const float* __restrict__ z2, const float* __restrict__ l2T,
    const float* __restrict__ lb, const float* __restrict__ w2pT,
    float* __restrict__ out) {
    const int bb = blockIdx.x >> 2, chunk = blockIdx.x & 3;
    __shared__ float h[32 * 256];
    __shared__ float sl[256];
    const int t = threadIdx.x;
    const float* zb = z2 + bb * 8192;
    for (int idx = t; idx < 8192; idx += 256) h[idx] = zb[idx];
    __syncthreads();
    float s = 0.f;
#pragma unroll
    for (int n = 0; n < 32; ++n) s += h[n * 256 + t];
    sl[t] = s * (1.f / 31.f);
    __syncthreads();
    const int o = t & 127, half = t >> 7;
    float c = lb[o];
#pragma unroll 4
    for (int d = 0; d < 256; ++d) c = fmaf(sl[d], l2T[d * 128 + o], c);
    float acc[4];
#pragma unroll
    for (int i = 0; i < 4; ++i) acc[i] = c;
    const int n0 = chunk * 8 + half * 4;
    for (int d0 = 0; d0 < 256; d0 += 4) {
        float wv0 = w2pT[(d0 + 0) * 128 + o];
        float wv1 = w2pT[(d0 + 1) * 128 + o];
        float wv2 = w2pT[(d0 + 2) * 128 + o];
        float wv3 = w2pT[(d0 + 3) * 128 + o];
#pragma unroll
        for (int ii = 0; ii < 4; ++ii) {
            f32x4 hv = *(const f32x4*)&h[(n0 + ii) * 256 + d0];
            acc[ii] = fmaf(hv[0], wv0, acc[ii]);
            acc[ii] = fmaf(hv[1], wv1, acc[ii]);
            acc[ii] = fmaf(hv[2], wv2, acc[ii]);
            acc[ii] = fmaf(hv[3], wv3, acc[ii]);
        }
    }
    for (int ii = 0; ii < 4; ++ii)
        out[(bb * 32 + n0 + ii) * 128 + o] = acc[ii];
}

extern "C" void kernel_launch(void* const* d_in, const int* in_sizes, int n_in,
                              void* d_out, int out_size, void* d_ws, size_t ws_size,
                              hipStream_t stream) {
    const float* x    = (const float*)d_in[0];
    const float* mask = (const float*)d_in[1];
    const float* c1w  = (const float*)d_in[2];
    const float* c1b  = (const float*)d_in[3];
    const float* c2w  = (const float*)d_in[4];
    const float* c2b  = (const float*)d_in[5];
    const float* fcw  = (const float*)d_in[6];
    const float* fcb  = (const float*)d_in[7];
    const float* s1lw = (const float*)d_in[8];
    const float* s1lb = (const float*)d_in[9];
    const float* s1rw = (const float*)d_in[10];
    const float* s2lw = (const float*)d_in[11];
    const float* s2lb = (const float*)d_in[12];
    const float* s2rw = (const float*)d_in[13];
    float* out = (float*)d_out;

    char* ws = (char*)d_ws;
    float* pooled = (float*)(ws);
    float* z1     = (float*)(ws + (512u  << 10));
    float* z2     = (float*)(ws + (1536u << 10));
    float* l1T    = (float*)(ws + (2560u << 10));
    float* w1pT   = (float*)(ws + (2816u << 10));
    float* l2T    = (float*)(ws + (3072u << 10));
    float* w2pT   = (float*)(ws + (3200u << 10));
    float* fwT    = (float*)(ws + (3328u << 10));
    short* w2b    = (short*)(ws + (3456u << 10));
    short* w1b    = (short*)(ws + (3600u << 10));

    prep_kernel<<<dim3(288), 256, 0, stream>>>(s1lw, s1rw, s2lw, s2rw, c2w, c1w, c1b,
                                               fcw, l1T, w1pT, l2T, w2pT, fwT, w2b, w1b);
    fused_conv_kernel<<<dim3(1024), 256, 0, stream>>>(x, w1b, w2b, c2b, pooled);
    fc_kernel<<<dim3(1024), 256, 0, stream>>>(pooled, fwT, fcb, mask, z1);
    sage1_kernel<<<dim3(128), 256, 0, stream>>>(z1, l1T, s1lb, w1pT, z2);
    sage2_kernel<<<dim3(128), 256, 0, stream>>>(z2, l2T, s2lb, w2pT, out);
}